// Round 12
// baseline (40.898 us; speedup 1.0000x reference)
//
#include <hip/hip_runtime.h>
#include <math.h>
#include <stdint.h>

#define N_TOK 8192
#define DIM   4096
#define NEXP  8
#define QD    1024                 // quarter of D per block
#define TPW   4                    // tokens per wave
#define QITER 4                    // 4 iters x 256 floats = QD
#define RING  3                    // x ring slots per wave (4 KB each)
#define WS_NEED ((size_t)N_TOK * 4 * NEXP * sizeof(float))   // part[n][q][e] = 1 MB

// Async global->LDS DMA, 16 B per lane: LDS dest = uniform base + lane*16,
// global src = per-lane address (m104/m108 semantics).
__device__ __forceinline__ void glds16(const float* gsrc, const float* lds_base,
                                       int lds_byte_off_uniform) {
    __builtin_amdgcn_global_load_lds(
        (const __attribute__((address_space(1))) uint32_t*)gsrc,
        (__attribute__((address_space(3))) uint32_t*)((char*)lds_base +
            __builtin_amdgcn_readfirstlane(lds_byte_off_uniform)),
        16, 0, 0);
}

// ---------------- K1: quarter-D partial logits via LDS-DMA streaming ----------
__global__ __launch_bounds__(256) void router_part_kernel(
    const float* __restrict__ x,     // [N_TOK, DIM]
    const float* __restrict__ w,     // [NEXP, DIM]
    float* __restrict__ part)        // [N_TOK][4][NEXP]
{
    __shared__ float wq[NEXP][QD];            // 32 KB (this block's d-quarter of w)
    __shared__ float xl[4][RING][TPW * 256];  // 48 KB (per-wave x rings)

    const int tid  = threadIdx.x;
    const int lane = tid & 63;
    const int wid  = tid >> 6;            // 0..3
    const int q    = blockIdx.x & 3;      // d-quarter
    const int blk  = blockIdx.x >> 2;     // 0..511
    const int n0   = blk * 16 + wid * TPW;

    // ---- stage w-quarter -> LDS via glds (wave w stages flat floats
    //      [wid*2048, wid*2048+2048) of the 8x1024 quarter) ----
    {
        const float* wg = w + q * QD;
        #pragma unroll
        for (int i = 0; i < 8; ++i) {
            const int f  = wid * 2048 + i * 256;    // wave-uniform flat float idx
            const int e  = f >> 10;                 // expert row
            const int d0 = f & 1023;                // offset within quarter
            glds16(wg + (size_t)e * DIM + d0 + lane * 4, &wq[0][0], f * 4);
        }
    }
    __syncthreads();   // drains w staging (vmcnt(0) here is fine, once)

    // ---- x ring prologue: issue slots 0,1,2 (12 glds, 1 KB each) ----
    const float* xq_ = x + q * QD + lane * 4;   // + n*DIM + j*256
    #pragma unroll
    for (int j = 0; j < RING; ++j)
        #pragma unroll
        for (int t = 0; t < TPW; ++t)
            glds16(xq_ + (size_t)(n0 + t) * DIM + j * 256,
                   &xl[0][0][0], ((wid * RING + j) * 1024 + t * 256) * 4);

    float acc[TPW][NEXP];
    #pragma unroll
    for (int t = 0; t < TPW; ++t)
        #pragma unroll
        for (int e = 0; e < NEXP; ++e) acc[t][e] = 0.0f;

    // ---- consume with per-wave counted vmcnt (no barriers in loop) ----
    #pragma unroll
    for (int j = 0; j < QITER; ++j) {
        // outstanding before wait: j=0:12, j=1:12, j=2:8, j=3:4 -> need slot j done
        if (j <= 1)      { asm volatile("s_waitcnt vmcnt(8)" ::: "memory"); }
        else if (j == 2) { asm volatile("s_waitcnt vmcnt(4)" ::: "memory"); }
        else             { asm volatile("s_waitcnt vmcnt(0)" ::: "memory"); }
        __builtin_amdgcn_sched_barrier(0);

        float4 wv[NEXP];
        #pragma unroll
        for (int e = 0; e < NEXP; ++e)
            wv[e] = *(const float4*)&wq[e][j * 256 + lane * 4];

        #pragma unroll
        for (int t = 0; t < TPW; ++t) {
            const float4 xv = *(const float4*)&xl[wid][j % RING][t * 256 + lane * 4];
            #pragma unroll
            for (int e = 0; e < NEXP; ++e) {
                acc[t][e] = fmaf(xv.x, wv[e].x,
                            fmaf(xv.y, wv[e].y,
                            fmaf(xv.z, wv[e].z,
                            fmaf(xv.w, wv[e].w, acc[t][e]))));
            }
        }

        if (j + RING < QITER) {   // refill the just-consumed slot (j==0 only)
            #pragma unroll
            for (int t = 0; t < TPW; ++t)
                glds16(xq_ + (size_t)(n0 + t) * DIM + (j + RING) * 256,
                       &xl[0][0][0],
                       ((wid * RING + (j + RING) % RING) * 1024 + t * 256) * 4);
        }
    }

    // ---- 64-lane butterfly -> full quarter-partial on every lane ----
    #pragma unroll
    for (int t = 0; t < TPW; ++t) {
        #pragma unroll
        for (int e = 0; e < NEXP; ++e) {
            float v = acc[t][e];
            #pragma unroll
            for (int off = 32; off >= 1; off >>= 1)
                v += __shfl_xor(v, off, 64);
            acc[t][e] = v;
        }
    }

    if (lane == 0) {
        #pragma unroll
        for (int t = 0; t < TPW; ++t) {
            float* p = part + ((size_t)(n0 + t) * 4 + q) * NEXP;
            *(float4*)(p + 0) = make_float4(acc[t][0], acc[t][1], acc[t][2], acc[t][3]);
            *(float4*)(p + 4) = make_float4(acc[t][4], acc[t][5], acc[t][6], acc[t][7]);
        }
    }
}

// ---------------- K2: combine 4 quarters + top-2 + renorm ----------------
__global__ __launch_bounds__(256) void router_top2_kernel(
    const float* __restrict__ part,  // [N_TOK][4][NEXP]
    float* __restrict__ out)         // [N_TOK*8] combine ++ [N_TOK*2] idx
{
    const int n = blockIdx.x * 256 + threadIdx.x;
    const float4* p = (const float4*)(part + (size_t)n * 32);

    // sum quarters sequentially (q0..q3), matching d-order
    float4 lo = p[0], hi = p[1];
    #pragma unroll
    for (int qq = 1; qq < 4; ++qq) {
        const float4 a = p[qq * 2], b = p[qq * 2 + 1];
        lo.x += a.x; lo.y += a.y; lo.z += a.z; lo.w += a.w;
        hi.x += b.x; hi.y += b.y; hi.z += b.z; hi.w += b.w;
    }
    float l[NEXP] = {lo.x, lo.y, lo.z, lo.w, hi.x, hi.y, hi.z, hi.w};

    // argmax: strict >, ascending scan => lowest index wins ties (lax.top_k)
    float m1 = l[0]; int i1 = 0;
    #pragma unroll
    for (int e = 1; e < NEXP; ++e)
        if (l[e] > m1) { m1 = l[e]; i1 = e; }
    float m2 = -INFINITY; int i2 = 0;
    #pragma unroll
    for (int e = 0; e < NEXP; ++e)
        if (e != i1 && l[e] > m2) { m2 = l[e]; i2 = e; }

    // softmax denom cancels under top-2 renorm
    const float e2  = expf(m2 - m1);
    const float inv = 1.0f / (1.0f + e2);
    const float w1  = inv;
    const float w2  = e2 * inv;

    float cmb[8];
    #pragma unroll
    for (int e = 0; e < 8; ++e)
        cmb[e] = (e == i1) ? w1 : ((e == i2) ? w2 : 0.0f);
    float4* cp = (float4*)(out + (size_t)n * 8);
    cp[0] = make_float4(cmb[0], cmb[1], cmb[2], cmb[3]);
    cp[1] = make_float4(cmb[4], cmb[5], cmb[6], cmb[7]);
    float* ip = out + (size_t)N_TOK * 8 + (size_t)n * 2;
    ip[0] = (float)i1;
    ip[1] = (float)i2;
}

// ---------------- Fallback (R4, known-correct 33 us) if ws too small ----------
#define TPWF  4
#define HALF  (DIM / 2)
#define FITER (HALF / 256)
__global__ __launch_bounds__(256) void router_fallback_kernel(
    const float* __restrict__ x, const float* __restrict__ w,
    float* __restrict__ out)
{
    __shared__ float red[2][TPWF][NEXP];
    const int lane = threadIdx.x & 63;
    const int wid  = threadIdx.x >> 6;
    const int g    = wid >> 1;
    const int h    = wid & 1;
    const int n0   = blockIdx.x * 8 + g * TPWF;

    float acc[TPWF][NEXP];
    #pragma unroll
    for (int t = 0; t < TPWF; ++t)
        #pragma unroll
        for (int e = 0; e < NEXP; ++e) acc[t][e] = 0.0f;

    const int dbase = h * HALF + lane * 4;
    const float* xr = x + (size_t)n0 * DIM + dbase;
    const float* wr = w + dbase;

    float4 xb[3][TPWF];
    #pragma unroll
    for (int t = 0; t < TPWF; ++t) xb[0][t] = *(const float4*)(xr + (size_t)t * DIM);
    #pragma unroll
    for (int t = 0; t < TPWF; ++t) xb[1][t] = *(const float4*)(xr + (size_t)t * DIM + 256);

    #pragma unroll
    for (int it = 0; it < FITER; ++it) {
        if (it + 2 < FITER) {
            const int off = (it + 2) * 256;
            #pragma unroll
            for (int t = 0; t < TPWF; ++t)
                xb[(it + 2) % 3][t] = *(const float4*)(xr + (size_t)t * DIM + off);
        }
        float4 wv[NEXP];
        #pragma unroll
        for (int e = 0; e < NEXP; ++e)
            wv[e] = *(const float4*)(wr + (size_t)e * DIM + it * 256);
        #pragma unroll
        for (int t = 0; t < TPWF; ++t) {
            const float4 xv = xb[it % 3][t];
            #pragma unroll
            for (int e = 0; e < NEXP; ++e)
                acc[t][e] = fmaf(xv.x, wv[e].x, fmaf(xv.y, wv[e].y,
                            fmaf(xv.z, wv[e].z, fmaf(xv.w, wv[e].w, acc[t][e]))));
        }
    }
    #pragma unroll
    for (int t = 0; t < TPWF; ++t)
        #pragma unroll
        for (int e = 0; e < NEXP; ++e) {
            float v = acc[t][e];
            #pragma unroll
            for (int off = 32; off >= 1; off >>= 1) v += __shfl_xor(v, off, 64);
            acc[t][e] = v;
        }
    if (h == 1 && lane == 0) {
        #pragma unroll
        for (int t = 0; t < TPWF; ++t) {
            *(float4*)&red[g][t][0] = make_float4(acc[t][0], acc[t][1], acc[t][2], acc[t][3]);
            *(float4*)&red[g][t][4] = make_float4(acc[t][4], acc[t][5], acc[t][6], acc[t][7]);
        }
    }
    __syncthreads();
    if (h == 0) {
        #pragma unroll
        for (int t = 0; t < TPWF; ++t) {
            float4 r0 = *(const float4*)&red[g][t][0];
            float4 r1 = *(const float4*)&red[g][t][4];
            acc[t][0] += r0.x; acc[t][1] += r0.y; acc[t][2] += r0.z; acc[t][3] += r0.w;
            acc[t][4] += r1.x; acc[t][5] += r1.y; acc[t][6] += r1.z; acc[t][7] += r1.w;
        }
        #pragma unroll
        for (int t = 0; t < TPWF; ++t) {
            float m1 = acc[t][0]; int i1 = 0;
            #pragma unroll
            for (int e = 1; e < NEXP; ++e)
                if (acc[t][e] > m1) { m1 = acc[t][e]; i1 = e; }
            float m2 = -INFINITY; int i2 = 0;
            #pragma unroll
            for (int e = 0; e < NEXP; ++e)
                if (e != i1 && acc[t][e] > m2) { m2 = acc[t][e]; i2 = e; }
            const float e2  = expf(m2 - m1);
            const float inv = 1.0f / (1.0f + e2);
            if (lane == 0) {
                const int n = n0 + t;
                float c[8];
                #pragma unroll
                for (int e = 0; e < 8; ++e)
                    c[e] = (e == i1) ? inv : ((e == i2) ? e2 * inv : 0.0f);
                float4* cp = (float4*)(out + (size_t)n * 8);
                cp[0] = make_float4(c[0], c[1], c[2], c[3]);
                cp[1] = make_float4(c[4], c[5], c[6], c[7]);
                float* ip = out + (size_t)N_TOK * 8 + (size_t)n * 2;
                ip[0] = (float)i1;
                ip[1] = (float)i2;
            }
        }
    }
}

extern "C" void kernel_launch(void* const* d_in, const int* in_sizes, int n_in,
                              void* d_out, int out_size, void* d_ws, size_t ws_size,
                              hipStream_t stream) {
    const float* x = (const float*)d_in[0];   // [8192, 4096] f32
    const float* w = (const float*)d_in[1];   // [8, 4096] f32
    float* out = (float*)d_out;

    if (ws_size >= WS_NEED) {
        float* part = (float*)d_ws;   // [N_TOK][4][NEXP], fully overwritten each call
        hipLaunchKernelGGL(router_part_kernel, dim3(2048), dim3(256), 0, stream,
                           x, w, part);
        hipLaunchKernelGGL(router_top2_kernel, dim3(N_TOK / 256), dim3(256), 0, stream,
                           part, out);
    } else {
        hipLaunchKernelGGL(router_fallback_kernel, dim3(N_TOK / 8), dim3(256), 0, stream,
                           x, w, out);
    }
}